// Round 5
// baseline (256.552 us; speedup 1.0000x reference)
//
#include <hip/hip_runtime.h>
#include <math.h>

#define Bq 4
#define Hh 8
#define Lh 2048
#define Dh 64
#define BH (Bq*Hh)

// ---------------- Kernel AC: fused kA (sampled-score partials) + kC (V col sums) ----
// kA layout = R0 proven (4-lane group/query, 2 shfl per 4-row batch).
// R5 change: the measured 42.7us matches a serial idx(200cy)->K(200cy) chain
// per batch (runtime-trip loop re-loads irow each iteration). For the common
// c0==20 case, preload ALL indices as 5x int4 up front and fully unroll the
// 5 batches -> no idx load, no loop control between batches; compiler can
// overlap batch b+1 loads with batch b compute without hand-built dbuf (R3's
// spill trap). Generic path kept verbatim for c0!=20.
__global__ __launch_bounds__(256) void kAC(const float* __restrict__ Q,
                                           const float* __restrict__ K,
                                           const float* __restrict__ V,
                                           const int* __restrict__ idxs,
                                           float2* __restrict__ M2,
                                           float* __restrict__ vpart, int u) {
    int bi = blockIdx.x;
    int tid = threadIdx.x;
    if (bi < 2048) {
        // ---- kA path ----
        int xcd = bi & 7, slot = bi >> 3;      // slot 0..255
        int bh  = xcd * 4 + (slot >> 6);       // 0..31
        int qt  = (slot >> 1) & 31;            // 0..31
        int half = slot & 1;
        int wave = tid >> 6, lane = tid & 63;
        int g = lane >> 2, c = lane & 3;       // 16 groups x 4 lanes
        int q = qt * 64 + wave * 16 + g;
        long gq = (long)bh * Lh + q;

        const float* qrow = Q + gq * Dh;
        float4 qf[4];
#pragma unroll
        for (int jj = 0; jj < 4; ++jj)
            qf[jj] = *(const float4*)(qrow + jj * 16 + c * 4);

        int cnt1 = u >> 1;                     // half1 count
        int c0 = (half == 0) ? (u - cnt1) : cnt1;
        const int* irow = idxs + (long)q * u + (half ? (u - cnt1) : 0);
        const float* kbase = K + (long)bh * Lh * Dh;

        float mx = -INFINITY, sm = 0.f;

#define KBATCH(I0v, I1v, I2v, I3v)                                           \
        {                                                                    \
            const float* kp0 = kbase + (long)(I0v) * Dh + c * 4;             \
            const float* kp1 = kbase + (long)(I1v) * Dh + c * 4;             \
            const float* kp2 = kbase + (long)(I2v) * Dh + c * 4;             \
            const float* kp3 = kbase + (long)(I3v) * Dh + c * 4;             \
            float4 kf[4][4];                                                 \
            _Pragma("unroll")                                                \
            for (int jj = 0; jj < 4; ++jj) {                                 \
                kf[0][jj] = *(const float4*)(kp0 + jj * 16);                 \
                kf[1][jj] = *(const float4*)(kp1 + jj * 16);                 \
                kf[2][jj] = *(const float4*)(kp2 + jj * 16);                 \
                kf[3][jj] = *(const float4*)(kp3 + jj * 16);                 \
            }                                                                \
            _Pragma("unroll")                                                \
            for (int r = 0; r < 4; ++r) {                                    \
                float a = 0.f;                                               \
                _Pragma("unroll")                                            \
                for (int jj = 0; jj < 4; ++jj)                               \
                    a += qf[jj].x*kf[r][jj].x + qf[jj].y*kf[r][jj].y         \
                       + qf[jj].z*kf[r][jj].z + qf[jj].w*kf[r][jj].w;        \
                a += __shfl_xor(a, 1);                                       \
                a += __shfl_xor(a, 2);                                       \
                mx = fmaxf(mx, a); sm += a;                                  \
            }                                                                \
        }

        if (c0 == 20) {
            // u==40 halves: irow 16B-aligned ((q*40+{0,20})*4 % 16 == 0).
            const int4* ip = (const int4*)irow;
            int4 Ia = ip[0], Ib = ip[1], Ic = ip[2], Id = ip[3], Ie = ip[4];
            KBATCH(Ia.x, Ia.y, Ia.z, Ia.w)
            KBATCH(Ib.x, Ib.y, Ib.z, Ib.w)
            KBATCH(Ic.x, Ic.y, Ic.z, Ic.w)
            KBATCH(Id.x, Id.y, Id.z, Id.w)
            KBATCH(Ie.x, Ie.y, Ie.z, Ie.w)
        } else {
            int s = 0;
            for (; s + 4 <= c0; s += 4) {
                int i0 = irow[s], i1 = irow[s+1], i2 = irow[s+2], i3 = irow[s+3];
                KBATCH(i0, i1, i2, i3)
            }
            for (; s < c0; ++s) {
                int ki = irow[s];
                const float* krow = kbase + (long)ki * Dh + c * 4;
                float acc = 0.f;
#pragma unroll
                for (int jj = 0; jj < 4; ++jj) {
                    float4 kf = *(const float4*)(krow + jj * 16);
                    acc += qf[jj].x*kf.x + qf[jj].y*kf.y + qf[jj].z*kf.z + qf[jj].w*kf.w;
                }
                acc += __shfl_xor(acc, 1);
                acc += __shfl_xor(acc, 2);
                mx = fmaxf(mx, acc); sm += acc;
            }
        }
#undef KBATCH
        if (c == 0) M2[gq * 2 + half] = make_float2(mx, sm);
    } else {
        // ---- kC path ----
        int b2 = bi - 2048;
        int xcd = b2 & 7, slot = b2 >> 3;
        int bh = xcd * 4 + (slot >> 3);
        int chunk = slot & 7;
        int d = tid & 63, r0 = tid >> 6;
        const float* vb = V + ((long)bh * Lh + chunk * 256) * Dh;
        float s = 0.f;
        for (int i = 0; i < 64; ++i) s += vb[(r0 + 4 * i) * Dh + d];
        __shared__ float part[4][64];
        part[r0][d] = s;
        __syncthreads();
        if (tid < 64) {
            float t = part[0][tid] + part[1][tid] + part[2][tid] + part[3][tid];
            vpart[(bh * 8 + chunk) * 64 + tid] = t;
        }
    }
}

// ---------------- Kernel BE: kE (mean fill) + kB (radix top-U) + cnt zero ---------
// blocks [0,4096): kE fill ctx with V-mean. [4096,4128): kB top-U per bh.
// block 4128: zero kD's split-K combine counters (ws is poisoned, can't assume 0).
__global__ __launch_bounds__(256) void kBE(const float2* __restrict__ M2,
                                           const float* __restrict__ vpart,
                                           int* __restrict__ topk,
                                           float* __restrict__ ctx,
                                           int* __restrict__ cnt,
                                           int U, int ncnt) {
    int bi = blockIdx.x;
    int tid = threadIdx.x;
    if (bi >= 4128) {
        if (tid < ncnt) cnt[tid] = 0;
        return;
    }
    if (bi < 4096) {
        // ---- kE path ----
        long base = (long)bi * 1024;
        int bh = (int)(base >> 17);
        __shared__ float vm[64];
        if (tid < 64) {
            float s = 0.f;
#pragma unroll
            for (int c2 = 0; c2 < 8; ++c2) s += vpart[(bh * 8 + c2) * 64 + tid];
            vm[tid] = s * (1.0f / (float)Lh);
        }
        __syncthreads();
        float4 val = *(const float4*)(vm + ((tid * 4) & 63));
        *(float4*)(ctx + base + tid * 4) = val;
        return;
    }
    // ---- kB path ----
    int bh = bi - 4096;
    unsigned key[8];
#pragma unroll
    for (int j = 0; j < 8; ++j) {
        long q = (long)bh * Lh + tid + 256 * j;
        float4 mm = *(const float4*)(&M2[q * 2]);   // {m0,s0,m1,s1}
        float Mv = fmaxf(mm.x, mm.z) - (mm.y + mm.w) * (1.0f / (float)Lh);
        unsigned ub = __float_as_uint(Mv);
        key[j] = ub ^ ((ub >> 31) ? 0xFFFFFFFFu : 0x80000000u);
    }
    __shared__ unsigned hist[256];
    __shared__ unsigned prefix_s;
    __shared__ int need_s;
    if (tid == 0) { prefix_s = 0u; need_s = U; }

    for (int level = 3; level >= 0; --level) {
        int shift = level * 8;
        hist[tid] = 0u;
        __syncthreads();
        unsigned prefix = prefix_s;
        int need = need_s;
        unsigned pmask = (level == 3) ? 0u : (0xFFFFFFFFu << (shift + 8));
#pragma unroll
        for (int j = 0; j < 8; ++j)
            if ((key[j] & pmask) == prefix)
                atomicAdd(&hist[(key[j] >> shift) & 0xFF], 1u);
        __syncthreads();
        if (tid < 64) {
            int lane = tid;
            unsigned h0 = hist[lane*4+0], h1 = hist[lane*4+1],
                     h2 = hist[lane*4+2], h3 = hist[lane*4+3];
            unsigned lt = h0 + h1 + h2 + h3;
            unsigned ssum = lt;
#pragma unroll
            for (int off = 1; off < 64; off <<= 1) {
                unsigned t = __shfl_down(ssum, off);
                if (lane + off < 64) ssum += t;
            }
            unsigned sx  = ssum - lt;
            unsigned suf3 = sx  + h3;
            unsigned suf2 = suf3 + h2;
            unsigned suf1 = suf2 + h1;
            unsigned suf0 = suf1 + h0;
            int localb = -1; unsigned nxt = 0u;
            if      ((int)suf3 >= need) { localb = lane*4+3; nxt = sx;   }
            else if ((int)suf2 >= need) { localb = lane*4+2; nxt = suf3; }
            else if ((int)suf1 >= need) { localb = lane*4+1; nxt = suf2; }
            else if ((int)suf0 >= need) { localb = lane*4+0; nxt = suf1; }
            unsigned long long ball = __ballot(localb >= 0);
            int hilane = 63 - __clzll(ball);
            if (lane == hilane) {
                prefix_s = prefix | ((unsigned)localb << shift);
                need_s = need - (int)nxt;
            }
        }
        __syncthreads();
    }
    unsigned T = prefix_s;
    int r = need_s;
    __shared__ int cgt, ceq;
    if (tid == 0) { cgt = 0; ceq = 0; }
    __syncthreads();
    int* out = topk + bh * U;
#pragma unroll
    for (int j = 0; j < 8; ++j) {
        if (key[j] > T) { int p = atomicAdd(&cgt, 1); out[p] = tid + 256 * j; }
        else if (key[j] == T) { int e = atomicAdd(&ceq, 1); if (e < r) out[U - r + e] = tid + 256 * j; }
    }
}

// ---------------- Kernel D: split-K partial attention + fused last-block combine ----
// R4's no-max softmax kept. R5: kF folded in via split-K pattern — after a
// block stores its partials: threadfence (all threads) -> sync -> tid0
// atomicAdd(cnt) -> last of 8 kc-blocks (device-scope) does the combine and
// scatters to ctx. Saves the kF launch + pacc round-trip drain.
#define TK 64
__global__ __launch_bounds__(256) void kD_part(const float* __restrict__ Q,
                                               const float* __restrict__ K,
                                               const float* __restrict__ V,
                                               const int* __restrict__ topk,
                                               float* __restrict__ pl,
                                               float* __restrict__ pacc,
                                               float* __restrict__ ctx,
                                               int* __restrict__ cnt,
                                               int U, int nch) {
    int bi = blockIdx.x;
    int xcd = bi & 7, slot = bi >> 3;
    int per = nch * 8;
    int bh = xcd * 4 + slot / per;
    int rest = slot % per;
    int uc = rest >> 3, kc = rest & 7;

    int tid = threadIdx.x;
    int wv = tid >> 6, lane = tid & 63;

    __shared__ float Qs[8 * 64];
    __shared__ float Ks[TK * 68];              // pad 68: conflict-free b128 rows
    __shared__ float Ps[8 * 68];
    __shared__ float lst[8];
    __shared__ int   qidxs[8];
    __shared__ int   lastflag;
    float* accbuf = Ks;                        // epilogue alias (2048 <= 4352 f)

    if (tid < 8) {
        int gu = uc * 8 + tid;
        qidxs[tid] = (gu < U) ? topk[bh * U + gu] : 0;
    }
    __syncthreads();
#pragma unroll
    for (int step = 0; step < 2; ++step) {
        int uu = step * 4 + wv;
        int row = qidxs[uu];
        Qs[uu * 64 + lane] = Q[((long)bh * Lh + row) * Dh + lane] * 0.125f;
    }
    // Qs visibility covered by first post-stage barrier below.

    int kq = lane, ug = wv;
    float plsum0 = 0.f, plsum1 = 0.f;          // lane-local exp-sums
    float accv[8] = {0.f,0.f,0.f,0.f,0.f,0.f,0.f,0.f};

    const long kvbase = (long)bh * Lh * Dh;
    const float4* Kg4 = (const float4*)(K + kvbase);
    const float*  Vg  = V + kvbase;
    int kbase0 = kc * 256;

    for (int t = 0; t < 4; ++t) {
        int t0 = kbase0 + t * TK;
        // ---- stage K tile: coalesced load -> immediate store (short liveness) ----
        int f40 = t0 * (Dh / 4);
#pragma unroll
        for (int j = 0; j < 4; ++j) {
            int i = tid + 256 * j;             // 0..1023 float4s
            float4 kv = Kg4[f40 + i];
            int row = i >> 4, col = i & 15;
            *(float4*)(&Ks[row * 68 + col * 4]) = kv;
        }
        __syncthreads();                       // K tile visible; prev Ps reads done

        // ---- scores for u = 2ug, 2ug+1 at key kq; p = exp(s) directly ----
        float s0 = 0.f, s1 = 0.f;
#pragma unroll
        for (int j16 = 0; j16 < 16; ++j16) {
            float4 kf = *(const float4*)(&Ks[kq * 68 + j16 * 4]);
            float4 qa = *(const float4*)(&Qs[(2 * ug + 0) * 64 + j16 * 4]);
            float4 qb = *(const float4*)(&Qs[(2 * ug + 1) * 64 + j16 * 4]);
            s0 += kf.x * qa.x + kf.y * qa.y + kf.z * qa.z + kf.w * qa.w;
            s1 += kf.x * qb.x + kf.y * qb.y + kf.z * qb.z + kf.w * qb.w;
        }
        float p0 = __expf(s0), p1 = __expf(s1);
        plsum0 += p0; plsum1 += p1;
        Ps[(2 * ug + 0) * 68 + kq] = p0;
        Ps[(2 * ug + 1) * 68 + kq] = p1;
        __syncthreads();                       // Ps visible; Ks reads done

        // ---- PV: lane=d, wave=key-quarter; V direct from global (coalesced) ----
        float vk[16];
        int vrow0 = t0 + wv * 16;
#pragma unroll
        for (int k = 0; k < 16; ++k)
            vk[k] = Vg[(long)(vrow0 + k) * Dh + lane];
#pragma unroll
        for (int u2 = 0; u2 < 8; ++u2) {
            const float* pb = &Ps[u2 * 68 + wv * 16];
            float4 pA = *(const float4*)(pb + 0);
            float4 pB = *(const float4*)(pb + 4);
            float4 pC = *(const float4*)(pb + 8);
            float4 pD = *(const float4*)(pb + 12);
            float ac = accv[u2];
            ac += pA.x*vk[0]  + pA.y*vk[1]  + pA.z*vk[2]  + pA.w*vk[3];
            ac += pB.x*vk[4]  + pB.y*vk[5]  + pB.z*vk[6]  + pB.w*vk[7];
            ac += pC.x*vk[8]  + pC.y*vk[9]  + pC.z*vk[10] + pC.w*vk[11];
            ac += pD.x*vk[12] + pD.y*vk[13] + pD.z*vk[14] + pD.w*vk[15];
            accv[u2] = ac;
        }
        // no barrier here: next stage's barrier orders Ps(t) reads vs Ps(t+1)
        // writes, and PV touches no Ks.
    }

    // single final l-reduce across the 64 key-lanes
#pragma unroll
    for (int off = 1; off < 64; off <<= 1) {
        plsum0 += __shfl_xor(plsum0, off);
        plsum1 += __shfl_xor(plsum1, off);
    }
    if (lane == 0) {
        lst[2 * ug] = plsum0;
        lst[2 * ug + 1] = plsum1;
    }
    // accbuf aliases Ks: safe — all Ks reads completed at last post-score barrier
#pragma unroll
    for (int u2 = 0; u2 < 8; ++u2)
        accbuf[wv * 512 + u2 * 64 + lane] = accv[u2];
    __syncthreads();

    int pbase = (bh * nch + uc) * 8;
    {
        int d = tid & 63, ua = tid >> 6;
#pragma unroll
        for (int h = 0; h < 2; ++h) {
            int u2 = ua + 4 * h;
            float o = accbuf[0 * 512 + u2 * 64 + d] + accbuf[1 * 512 + u2 * 64 + d]
                    + accbuf[2 * 512 + u2 * 64 + d] + accbuf[3 * 512 + u2 * 64 + d];
            pacc[((long)(pbase + u2) * 8 + kc) * 64 + d] = o;
        }
    }
    if (tid < 8) {
        int qp = (pbase + tid) * 8 + kc;
        pl[qp] = lst[tid];
    }

    // ---- split-K last-block combine (was kernel F) ----
    __threadfence();                           // each thread: release my stores
    __syncthreads();                           // all fences done
    if (tid == 0) {
        int old = atomicAdd(&cnt[bh * nch + uc], 1);
        lastflag = (old == 7) ? 1 : 0;
    }
    __syncthreads();
    if (lastflag) {
        __threadfence();                       // acquire: see peers' stores
        int u2 = tid >> 5, t = tid & 31;
        int gu = uc * 8 + u2;
        if (gu < U) {
            int qbase = pbase + u2;
            float gl = 0.f;
#pragma unroll
            for (int k2 = 0; k2 < 8; ++k2) gl += pl[qbase * 8 + k2];
            float inv = 1.0f / gl;
            float o0 = 0.f, o1 = 0.f;
#pragma unroll
            for (int k2 = 0; k2 < 8; ++k2) {
                const float* a = pacc + ((long)qbase * 8 + k2) * 64;
                o0 += a[t];
                o1 += a[t + 32];
            }
            int row = topk[bh * U + gu];
            float* crow = ctx + ((long)bh * Lh + row) * Dh;
            crow[t]      = o0 * inv;
            crow[t + 32] = o1 * inv;
        }
    }
}

extern "C" void kernel_launch(void* const* d_in, const int* in_sizes, int n_in,
                              void* d_out, int out_size, void* d_ws, size_t ws_size,
                              hipStream_t stream) {
    const float* Q    = (const float*)d_in[0];
    const float* K    = (const float*)d_in[1];
    const float* V    = (const float*)d_in[2];
    const int*   idxs = (const int*)d_in[3];
    float* ctx = (float*)d_out;

    int u = in_sizes[3] / Lh;    // 40
    int U = u;
    int nch = (U + 7) / 8;       // 5
    int ncnt = 32 * nch;         // 160 combine counters

    // workspace layout (floats)
    float*  wsf   = (float*)d_ws;
    float2* M2    = (float2*)wsf;                    // 131072 float2 = 262144 f
    int*    topk  = (int*)(wsf + 262144);            // 2048 ints
    float*  vpart = wsf + 262144 + 2048;             // 16384 f
    float*  pl    = wsf + 280576;                    // 32*nch*8*8
    float*  pacc  = pl + 32 * nch * 8 * 8;           // 32*nch*8*8*64
    int*    cnt   = (int*)(pacc + (long)32 * nch * 8 * 8 * 64);

    kAC    <<<2304,         256, 0, stream>>>(Q, K, V, idxs, M2, vpart, u);
    kBE    <<<4129,         256, 0, stream>>>(M2, vpart, topk, ctx, cnt, U, ncnt);
    kD_part<<<BH * nch * 8, 256, 0, stream>>>(Q, K, V, topk, pl, pacc, ctx, cnt, U, nch);
}

// Round 6
// 157.774 us; speedup vs baseline: 1.6261x; 1.6261x over previous
//
#include <hip/hip_runtime.h>
#include <math.h>

#define Bq 4
#define Hh 8
#define Lh 2048
#define Dh 64
#define BH (Bq*Hh)

// ---------------- Kernel AC: fused kA (sampled-score partials) + kC (V col sums) ----
// kA layout = R0 proven (4-lane group/query, 2 shfl per 4-row batch).
// R5/R6: for the common c0==20 case preload ALL indices as 5x int4 up front
// and fully unroll the 5 batches -> no idx load / loop control between
// batches; compiler may overlap batch b+1 loads with batch b compute without
// hand-built dbuf (R3's spill trap). Generic path kept for c0!=20.
__global__ __launch_bounds__(256) void kAC(const float* __restrict__ Q,
                                           const float* __restrict__ K,
                                           const float* __restrict__ V,
                                           const int* __restrict__ idxs,
                                           float2* __restrict__ M2,
                                           float* __restrict__ vpart, int u) {
    int bi = blockIdx.x;
    int tid = threadIdx.x;
    if (bi < 2048) {
        // ---- kA path ----
        int xcd = bi & 7, slot = bi >> 3;      // slot 0..255
        int bh  = xcd * 4 + (slot >> 6);       // 0..31
        int qt  = (slot >> 1) & 31;            // 0..31
        int half = slot & 1;
        int wave = tid >> 6, lane = tid & 63;
        int g = lane >> 2, c = lane & 3;       // 16 groups x 4 lanes
        int q = qt * 64 + wave * 16 + g;
        long gq = (long)bh * Lh + q;

        const float* qrow = Q + gq * Dh;
        float4 qf[4];
#pragma unroll
        for (int jj = 0; jj < 4; ++jj)
            qf[jj] = *(const float4*)(qrow + jj * 16 + c * 4);

        int cnt1 = u >> 1;                     // half1 count
        int c0 = (half == 0) ? (u - cnt1) : cnt1;
        const int* irow = idxs + (long)q * u + (half ? (u - cnt1) : 0);
        const float* kbase = K + (long)bh * Lh * Dh;

        float mx = -INFINITY, sm = 0.f;

#define KBATCH(I0v, I1v, I2v, I3v)                                           \
        {                                                                    \
            const float* kp0 = kbase + (long)(I0v) * Dh + c * 4;             \
            const float* kp1 = kbase + (long)(I1v) * Dh + c * 4;             \
            const float* kp2 = kbase + (long)(I2v) * Dh + c * 4;             \
            const float* kp3 = kbase + (long)(I3v) * Dh + c * 4;             \
            float4 kf[4][4];                                                 \
            _Pragma("unroll")                                                \
            for (int jj = 0; jj < 4; ++jj) {                                 \
                kf[0][jj] = *(const float4*)(kp0 + jj * 16);                 \
                kf[1][jj] = *(const float4*)(kp1 + jj * 16);                 \
                kf[2][jj] = *(const float4*)(kp2 + jj * 16);                 \
                kf[3][jj] = *(const float4*)(kp3 + jj * 16);                 \
            }                                                                \
            _Pragma("unroll")                                                \
            for (int r = 0; r < 4; ++r) {                                    \
                float a = 0.f;                                               \
                _Pragma("unroll")                                            \
                for (int jj = 0; jj < 4; ++jj)                               \
                    a += qf[jj].x*kf[r][jj].x + qf[jj].y*kf[r][jj].y         \
                       + qf[jj].z*kf[r][jj].z + qf[jj].w*kf[r][jj].w;        \
                a += __shfl_xor(a, 1);                                       \
                a += __shfl_xor(a, 2);                                       \
                mx = fmaxf(mx, a); sm += a;                                  \
            }                                                                \
        }

        if (c0 == 20) {
            // u==40 halves: irow 16B-aligned ((q*40+{0,20})*4 % 16 == 0).
            const int4* ip = (const int4*)irow;
            int4 Ia = ip[0], Ib = ip[1], Ic = ip[2], Id = ip[3], Ie = ip[4];
            KBATCH(Ia.x, Ia.y, Ia.z, Ia.w)
            KBATCH(Ib.x, Ib.y, Ib.z, Ib.w)
            KBATCH(Ic.x, Ic.y, Ic.z, Ic.w)
            KBATCH(Id.x, Id.y, Id.z, Id.w)
            KBATCH(Ie.x, Ie.y, Ie.z, Ie.w)
        } else {
            int s = 0;
            for (; s + 4 <= c0; s += 4) {
                int i0 = irow[s], i1 = irow[s+1], i2 = irow[s+2], i3 = irow[s+3];
                KBATCH(i0, i1, i2, i3)
            }
            for (; s < c0; ++s) {
                int ki = irow[s];
                const float* krow = kbase + (long)ki * Dh + c * 4;
                float acc = 0.f;
#pragma unroll
                for (int jj = 0; jj < 4; ++jj) {
                    float4 kf = *(const float4*)(krow + jj * 16);
                    acc += qf[jj].x*kf.x + qf[jj].y*kf.y + qf[jj].z*kf.z + qf[jj].w*kf.w;
                }
                acc += __shfl_xor(acc, 1);
                acc += __shfl_xor(acc, 2);
                mx = fmaxf(mx, acc); sm += acc;
            }
        }
#undef KBATCH
        if (c == 0) M2[gq * 2 + half] = make_float2(mx, sm);
    } else {
        // ---- kC path ----
        int b2 = bi - 2048;
        int xcd = b2 & 7, slot = b2 >> 3;
        int bh = xcd * 4 + (slot >> 3);
        int chunk = slot & 7;
        int d = tid & 63, r0 = tid >> 6;
        const float* vb = V + ((long)bh * Lh + chunk * 256) * Dh;
        float s = 0.f;
        for (int i = 0; i < 64; ++i) s += vb[(r0 + 4 * i) * Dh + d];
        __shared__ float part[4][64];
        part[r0][d] = s;
        __syncthreads();
        if (tid < 64) {
            float t = part[0][tid] + part[1][tid] + part[2][tid] + part[3][tid];
            vpart[(bh * 8 + chunk) * 64 + tid] = t;
        }
    }
}

// ---------------- Kernel BE: fused kE (mean fill) + kB (radix top-U) ----------------
// R4 exact. blocks [0,4096): kE fill ctx with V-mean. [4096,4128): kB top-U.
// R5 lesson: device-scope fences in a wide kernel (kD fused combine) cost
// ~110us — L2 writeback per block on non-coherent XCD L2s. Separate kF kept.
__global__ __launch_bounds__(256) void kBE(const float2* __restrict__ M2,
                                           const float* __restrict__ vpart,
                                           int* __restrict__ topk,
                                           float* __restrict__ ctx, int U) {
    int bi = blockIdx.x;
    int tid = threadIdx.x;
    if (bi < 4096) {
        // ---- kE path ----
        long base = (long)bi * 1024;
        int bh = (int)(base >> 17);
        __shared__ float vm[64];
        if (tid < 64) {
            float s = 0.f;
#pragma unroll
            for (int c2 = 0; c2 < 8; ++c2) s += vpart[(bh * 8 + c2) * 64 + tid];
            vm[tid] = s * (1.0f / (float)Lh);
        }
        __syncthreads();
        float4 val = *(const float4*)(vm + ((tid * 4) & 63));
        *(float4*)(ctx + base + tid * 4) = val;
        return;
    }
    // ---- kB path ----
    int bh = bi - 4096;
    unsigned key[8];
#pragma unroll
    for (int j = 0; j < 8; ++j) {
        long q = (long)bh * Lh + tid + 256 * j;
        float4 mm = *(const float4*)(&M2[q * 2]);   // {m0,s0,m1,s1}
        float Mv = fmaxf(mm.x, mm.z) - (mm.y + mm.w) * (1.0f / (float)Lh);
        unsigned ub = __float_as_uint(Mv);
        key[j] = ub ^ ((ub >> 31) ? 0xFFFFFFFFu : 0x80000000u);
    }
    __shared__ unsigned hist[256];
    __shared__ unsigned prefix_s;
    __shared__ int need_s;
    if (tid == 0) { prefix_s = 0u; need_s = U; }

    for (int level = 3; level >= 0; --level) {
        int shift = level * 8;
        hist[tid] = 0u;
        __syncthreads();
        unsigned prefix = prefix_s;
        int need = need_s;
        unsigned pmask = (level == 3) ? 0u : (0xFFFFFFFFu << (shift + 8));
#pragma unroll
        for (int j = 0; j < 8; ++j)
            if ((key[j] & pmask) == prefix)
                atomicAdd(&hist[(key[j] >> shift) & 0xFF], 1u);
        __syncthreads();
        if (tid < 64) {
            int lane = tid;
            unsigned h0 = hist[lane*4+0], h1 = hist[lane*4+1],
                     h2 = hist[lane*4+2], h3 = hist[lane*4+3];
            unsigned lt = h0 + h1 + h2 + h3;
            unsigned ssum = lt;
#pragma unroll
            for (int off = 1; off < 64; off <<= 1) {
                unsigned t = __shfl_down(ssum, off);
                if (lane + off < 64) ssum += t;
            }
            unsigned sx  = ssum - lt;
            unsigned suf3 = sx  + h3;
            unsigned suf2 = suf3 + h2;
            unsigned suf1 = suf2 + h1;
            unsigned suf0 = suf1 + h0;
            int localb = -1; unsigned nxt = 0u;
            if      ((int)suf3 >= need) { localb = lane*4+3; nxt = sx;   }
            else if ((int)suf2 >= need) { localb = lane*4+2; nxt = suf3; }
            else if ((int)suf1 >= need) { localb = lane*4+1; nxt = suf2; }
            else if ((int)suf0 >= need) { localb = lane*4+0; nxt = suf1; }
            unsigned long long ball = __ballot(localb >= 0);
            int hilane = 63 - __clzll(ball);
            if (lane == hilane) {
                prefix_s = prefix | ((unsigned)localb << shift);
                need_s = need - (int)nxt;
            }
        }
        __syncthreads();
    }
    unsigned T = prefix_s;
    int r = need_s;
    __shared__ int cgt, ceq;
    if (tid == 0) { cgt = 0; ceq = 0; }
    __syncthreads();
    int* out = topk + bh * U;
#pragma unroll
    for (int j = 0; j < 8; ++j) {
        if (key[j] > T) { int p = atomicAdd(&cgt, 1); out[p] = tid + 256 * j; }
        else if (key[j] == T) { int e = atomicAdd(&ceq, 1); if (e < r) out[U - r + e] = tid + 256 * j; }
    }
}

// ---------------- Kernel D: split-K partial attention, NO-MAX softmax (R4 exact) ----
#define TK 64
__global__ __launch_bounds__(256) void kD_part(const float* __restrict__ Q,
                                               const float* __restrict__ K,
                                               const float* __restrict__ V,
                                               const int* __restrict__ topk,
                                               float* __restrict__ pl,
                                               float* __restrict__ pacc,
                                               int U, int nch) {
    int bi = blockIdx.x;
    int xcd = bi & 7, slot = bi >> 3;
    int per = nch * 8;
    int bh = xcd * 4 + slot / per;
    int rest = slot % per;
    int uc = rest >> 3, kc = rest & 7;

    int tid = threadIdx.x;
    int wv = tid >> 6, lane = tid & 63;

    __shared__ float Qs[8 * 64];
    __shared__ float Ks[TK * 68];              // pad 68: conflict-free b128 rows
    __shared__ float Ps[8 * 68];
    __shared__ float lst[8];
    __shared__ int   qidxs[8];
    float* accbuf = Ks;                        // epilogue alias (2048 <= 4352 f)

    if (tid < 8) {
        int gu = uc * 8 + tid;
        qidxs[tid] = (gu < U) ? topk[bh * U + gu] : 0;
    }
    __syncthreads();
#pragma unroll
    for (int step = 0; step < 2; ++step) {
        int uu = step * 4 + wv;
        int row = qidxs[uu];
        Qs[uu * 64 + lane] = Q[((long)bh * Lh + row) * Dh + lane] * 0.125f;
    }
    // Qs visibility covered by first post-stage barrier below.

    int kq = lane, ug = wv;
    float plsum0 = 0.f, plsum1 = 0.f;          // lane-local exp-sums
    float accv[8] = {0.f,0.f,0.f,0.f,0.f,0.f,0.f,0.f};

    const long kvbase = (long)bh * Lh * Dh;
    const float4* Kg4 = (const float4*)(K + kvbase);
    const float*  Vg  = V + kvbase;
    int kbase0 = kc * 256;

    for (int t = 0; t < 4; ++t) {
        int t0 = kbase0 + t * TK;
        // ---- stage K tile: coalesced load -> immediate store (short liveness) ----
        int f40 = t0 * (Dh / 4);
#pragma unroll
        for (int j = 0; j < 4; ++j) {
            int i = tid + 256 * j;             // 0..1023 float4s
            float4 kv = Kg4[f40 + i];
            int row = i >> 4, col = i & 15;
            *(float4*)(&Ks[row * 68 + col * 4]) = kv;
        }
        __syncthreads();                       // K tile visible; prev Ps reads done

        // ---- scores for u = 2ug, 2ug+1 at key kq; p = exp(s) directly ----
        float s0 = 0.f, s1 = 0.f;
#pragma unroll
        for (int j16 = 0; j16 < 16; ++j16) {
            float4 kf = *(const float4*)(&Ks[kq * 68 + j16 * 4]);
            float4 qa = *(const float4*)(&Qs[(2 * ug + 0) * 64 + j16 * 4]);
            float4 qb = *(const float4*)(&Qs[(2 * ug + 1) * 64 + j16 * 4]);
            s0 += kf.x * qa.x + kf.y * qa.y + kf.z * qa.z + kf.w * qa.w;
            s1 += kf.x * qb.x + kf.y * qb.y + kf.z * qb.z + kf.w * qb.w;
        }
        float p0 = __expf(s0), p1 = __expf(s1);
        plsum0 += p0; plsum1 += p1;
        Ps[(2 * ug + 0) * 68 + kq] = p0;
        Ps[(2 * ug + 1) * 68 + kq] = p1;
        __syncthreads();                       // Ps visible; Ks reads done

        // ---- PV: lane=d, wave=key-quarter; V direct from global (coalesced) ----
        float vk[16];
        int vrow0 = t0 + wv * 16;
#pragma unroll
        for (int k = 0; k < 16; ++k)
            vk[k] = Vg[(long)(vrow0 + k) * Dh + lane];
#pragma unroll
        for (int u2 = 0; u2 < 8; ++u2) {
            const float* pb = &Ps[u2 * 68 + wv * 16];
            float4 pA = *(const float4*)(pb + 0);
            float4 pB = *(const float4*)(pb + 4);
            float4 pC = *(const float4*)(pb + 8);
            float4 pD = *(const float4*)(pb + 12);
            float ac = accv[u2];
            ac += pA.x*vk[0]  + pA.y*vk[1]  + pA.z*vk[2]  + pA.w*vk[3];
            ac += pB.x*vk[4]  + pB.y*vk[5]  + pB.z*vk[6]  + pB.w*vk[7];
            ac += pC.x*vk[8]  + pC.y*vk[9]  + pC.z*vk[10] + pC.w*vk[11];
            ac += pD.x*vk[12] + pD.y*vk[13] + pD.z*vk[14] + pD.w*vk[15];
            accv[u2] = ac;
        }
        // no barrier here: next stage's barrier orders Ps(t) reads vs Ps(t+1)
        // writes, and PV touches no Ks.
    }

    // single final l-reduce across the 64 key-lanes (was per-tile before)
#pragma unroll
    for (int off = 1; off < 64; off <<= 1) {
        plsum0 += __shfl_xor(plsum0, off);
        plsum1 += __shfl_xor(plsum1, off);
    }
    if (lane == 0) {
        lst[2 * ug] = plsum0;
        lst[2 * ug + 1] = plsum1;
    }
    // accbuf aliases Ks: safe — all Ks reads completed at last post-score barrier
#pragma unroll
    for (int u2 = 0; u2 < 8; ++u2)
        accbuf[wv * 512 + u2 * 64 + lane] = accv[u2];
    __syncthreads();

    int pbase = (bh * nch + uc) * 8;
    {
        int d = tid & 63, ua = tid >> 6;
#pragma unroll
        for (int h = 0; h < 2; ++h) {
            int u2 = ua + 4 * h;
            float o = accbuf[0 * 512 + u2 * 64 + d] + accbuf[1 * 512 + u2 * 64 + d]
                    + accbuf[2 * 512 + u2 * 64 + d] + accbuf[3 * 512 + u2 * 64 + d];
            pacc[((long)(pbase + u2) * 8 + kc) * 64 + d] = o;
        }
    }
    if (tid < 8) {
        int qp = (pbase + tid) * 8 + kc;
        pl[qp] = lst[tid];
    }
}

// ---------------- Kernel F: combine split-K partials (plain sums), scatter ----------
__global__ __launch_bounds__(256) void kF_comb(const float* __restrict__ pl,
                                               const float* __restrict__ pacc,
                                               const int* __restrict__ topk,
                                               float* __restrict__ ctx,
                                               int U, int nch) {
    int bi = blockIdx.x;
    int bh = bi / nch, uc = bi % nch;
    int tid = threadIdx.x;
    int u = tid >> 5, t = tid & 31;
    int gu = uc * 8 + u;
    if (gu >= U) return;
    int qbase = (bh * nch + uc) * 8 + u;
    float gl = 0.f;
#pragma unroll
    for (int kc = 0; kc < 8; ++kc) gl += pl[qbase * 8 + kc];
    float inv = 1.0f / gl;
    float o0 = 0.f, o1 = 0.f;
#pragma unroll
    for (int kc = 0; kc < 8; ++kc) {
        const float* a = pacc + ((long)qbase * 8 + kc) * 64;
        o0 += a[t];
        o1 += a[t + 32];
    }
    int row = topk[bh * U + gu];
    float* crow = ctx + ((long)bh * Lh + row) * Dh;
    crow[t]      = o0 * inv;
    crow[t + 32] = o1 * inv;
}

extern "C" void kernel_launch(void* const* d_in, const int* in_sizes, int n_in,
                              void* d_out, int out_size, void* d_ws, size_t ws_size,
                              hipStream_t stream) {
    const float* Q    = (const float*)d_in[0];
    const float* K    = (const float*)d_in[1];
    const float* V    = (const float*)d_in[2];
    const int*   idxs = (const int*)d_in[3];
    float* ctx = (float*)d_out;

    int u = in_sizes[3] / Lh;    // 40
    int U = u;
    int nch = (U + 7) / 8;       // 5

    // workspace layout (floats)
    float*  wsf   = (float*)d_ws;
    float2* M2    = (float2*)wsf;                    // 131072 float2 = 262144 f
    int*    topk  = (int*)(wsf + 262144);            // 2048 ints
    float*  vpart = wsf + 262144 + 2048;             // 16384 f
    float*  pl    = wsf + 280576;                    // 32*nch*8*8
    float*  pacc  = pl + 32 * nch * 8 * 8;           // 32*nch*8*8*64

    kAC    <<<2304,         256, 0, stream>>>(Q, K, V, idxs, M2, vpart, u);
    kBE    <<<4128,         256, 0, stream>>>(M2, vpart, topk, ctx, U);
    kD_part<<<BH * nch * 8, 256, 0, stream>>>(Q, K, V, topk, pl, pacc, U, nch);
    kF_comb<<<BH * nch,     256, 0, stream>>>(pl, pacc, topk, ctx, U, nch);
}

// Round 7
// 154.309 us; speedup vs baseline: 1.6626x; 1.0225x over previous
//
#include <hip/hip_runtime.h>
#include <math.h>

#define Bq 4
#define Hh 8
#define Lh 2048
#define Dh 64
#define BH (Bq*Hh)

// ---------------- Kernel AC: fused kA (sampled-score partials) + kC (V col sums) ----
// kA: R0-EXACT. Four restructures (R1 shuffle-heavy, R2 LDS-staged, R3 reg-dbuf
// spill, R6 int4+full-unroll) all regressed vs this plain loop. ~43us is the
// scattered-256B-gather floor (~0.45 req/cy/CU); DO NOT TOUCH.
__global__ __launch_bounds__(256) void kAC(const float* __restrict__ Q,
                                           const float* __restrict__ K,
                                           const float* __restrict__ V,
                                           const int* __restrict__ idxs,
                                           float2* __restrict__ M2,
                                           float* __restrict__ vpart, int u) {
    int bi = blockIdx.x;
    int tid = threadIdx.x;
    if (bi < 2048) {
        // ---- kA path ----
        int xcd = bi & 7, slot = bi >> 3;      // slot 0..255
        int bh  = xcd * 4 + (slot >> 6);       // 0..31
        int qt  = (slot >> 1) & 31;            // 0..31
        int half = slot & 1;
        int wave = tid >> 6, lane = tid & 63;
        int g = lane >> 2, c = lane & 3;       // 16 groups x 4 lanes
        int q = qt * 64 + wave * 16 + g;
        long gq = (long)bh * Lh + q;

        const float* qrow = Q + gq * Dh;
        float4 qf[4];
#pragma unroll
        for (int jj = 0; jj < 4; ++jj)
            qf[jj] = *(const float4*)(qrow + jj * 16 + c * 4);

        int cnt1 = u >> 1;                     // half1 count
        int c0 = (half == 0) ? (u - cnt1) : cnt1;
        const int* irow = idxs + (long)q * u + (half ? (u - cnt1) : 0);
        const float* kbase = K + (long)bh * Lh * Dh;

        float mx = -INFINITY, sm = 0.f;
        int s = 0;
        for (; s + 4 <= c0; s += 4) {
            int i0 = irow[s], i1 = irow[s+1], i2 = irow[s+2], i3 = irow[s+3];
            const float* kp0 = kbase + (long)i0 * Dh + c * 4;
            const float* kp1 = kbase + (long)i1 * Dh + c * 4;
            const float* kp2 = kbase + (long)i2 * Dh + c * 4;
            const float* kp3 = kbase + (long)i3 * Dh + c * 4;
            float4 kf[4][4];
#pragma unroll
            for (int jj = 0; jj < 4; ++jj) {
                kf[0][jj] = *(const float4*)(kp0 + jj * 16);
                kf[1][jj] = *(const float4*)(kp1 + jj * 16);
                kf[2][jj] = *(const float4*)(kp2 + jj * 16);
                kf[3][jj] = *(const float4*)(kp3 + jj * 16);
            }
            float a[4];
#pragma unroll
            for (int r = 0; r < 4; ++r) {
                float ac = 0.f;
#pragma unroll
                for (int jj = 0; jj < 4; ++jj)
                    ac += qf[jj].x*kf[r][jj].x + qf[jj].y*kf[r][jj].y
                        + qf[jj].z*kf[r][jj].z + qf[jj].w*kf[r][jj].w;
                a[r] = ac;
            }
#pragma unroll
            for (int r = 0; r < 4; ++r) {
                a[r] += __shfl_xor(a[r], 1);
                a[r] += __shfl_xor(a[r], 2);
                mx = fmaxf(mx, a[r]); sm += a[r];
            }
        }
        for (; s < c0; ++s) {
            int ki = irow[s];
            const float* krow = kbase + (long)ki * Dh + c * 4;
            float acc = 0.f;
#pragma unroll
            for (int jj = 0; jj < 4; ++jj) {
                float4 kf = *(const float4*)(krow + jj * 16);
                acc += qf[jj].x*kf.x + qf[jj].y*kf.y + qf[jj].z*kf.z + qf[jj].w*kf.w;
            }
            acc += __shfl_xor(acc, 1);
            acc += __shfl_xor(acc, 2);
            mx = fmaxf(mx, acc); sm += acc;
        }
        if (c == 0) M2[gq * 2 + half] = make_float2(mx, sm);
    } else {
        // ---- kC path ----
        int b2 = bi - 2048;
        int xcd = b2 & 7, slot = b2 >> 3;
        int bh = xcd * 4 + (slot >> 3);
        int chunk = slot & 7;
        int d = tid & 63, r0 = tid >> 6;
        const float* vb = V + ((long)bh * Lh + chunk * 256) * Dh;
        float s = 0.f;
        for (int i = 0; i < 64; ++i) s += vb[(r0 + 4 * i) * Dh + d];
        __shared__ float part[4][64];
        part[r0][d] = s;
        __syncthreads();
        if (tid < 64) {
            float t = part[0][tid] + part[1][tid] + part[2][tid] + part[3][tid];
            vpart[(bh * 8 + chunk) * 64 + tid] = t;
        }
    }
}

// ---------------- Kernel BE: fused kE (mean fill) + kB (radix top-U) ----------------
// R4 exact. blocks [0,4096): kE fill ctx with V-mean. [4096,4128): kB top-U.
__global__ __launch_bounds__(256) void kBE(const float2* __restrict__ M2,
                                           const float* __restrict__ vpart,
                                           int* __restrict__ topk,
                                           float* __restrict__ ctx, int U) {
    int bi = blockIdx.x;
    int tid = threadIdx.x;
    if (bi < 4096) {
        // ---- kE path ----
        long base = (long)bi * 1024;
        int bh = (int)(base >> 17);
        __shared__ float vm[64];
        if (tid < 64) {
            float s = 0.f;
#pragma unroll
            for (int c2 = 0; c2 < 8; ++c2) s += vpart[(bh * 8 + c2) * 64 + tid];
            vm[tid] = s * (1.0f / (float)Lh);
        }
        __syncthreads();
        float4 val = *(const float4*)(vm + ((tid * 4) & 63));
        *(float4*)(ctx + base + tid * 4) = val;
        return;
    }
    // ---- kB path ----
    int bh = bi - 4096;
    unsigned key[8];
#pragma unroll
    for (int j = 0; j < 8; ++j) {
        long q = (long)bh * Lh + tid + 256 * j;
        float4 mm = *(const float4*)(&M2[q * 2]);   // {m0,s0,m1,s1}
        float Mv = fmaxf(mm.x, mm.z) - (mm.y + mm.w) * (1.0f / (float)Lh);
        unsigned ub = __float_as_uint(Mv);
        key[j] = ub ^ ((ub >> 31) ? 0xFFFFFFFFu : 0x80000000u);
    }
    __shared__ unsigned hist[256];
    __shared__ unsigned prefix_s;
    __shared__ int need_s;
    if (tid == 0) { prefix_s = 0u; need_s = U; }

    for (int level = 3; level >= 0; --level) {
        int shift = level * 8;
        hist[tid] = 0u;
        __syncthreads();
        unsigned prefix = prefix_s;
        int need = need_s;
        unsigned pmask = (level == 3) ? 0u : (0xFFFFFFFFu << (shift + 8));
#pragma unroll
        for (int j = 0; j < 8; ++j)
            if ((key[j] & pmask) == prefix)
                atomicAdd(&hist[(key[j] >> shift) & 0xFF], 1u);
        __syncthreads();
        if (tid < 64) {
            int lane = tid;
            unsigned h0 = hist[lane*4+0], h1 = hist[lane*4+1],
                     h2 = hist[lane*4+2], h3 = hist[lane*4+3];
            unsigned lt = h0 + h1 + h2 + h3;
            unsigned ssum = lt;
#pragma unroll
            for (int off = 1; off < 64; off <<= 1) {
                unsigned t = __shfl_down(ssum, off);
                if (lane + off < 64) ssum += t;
            }
            unsigned sx  = ssum - lt;
            unsigned suf3 = sx  + h3;
            unsigned suf2 = suf3 + h2;
            unsigned suf1 = suf2 + h1;
            unsigned suf0 = suf1 + h0;
            int localb = -1; unsigned nxt = 0u;
            if      ((int)suf3 >= need) { localb = lane*4+3; nxt = sx;   }
            else if ((int)suf2 >= need) { localb = lane*4+2; nxt = suf3; }
            else if ((int)suf1 >= need) { localb = lane*4+1; nxt = suf2; }
            else if ((int)suf0 >= need) { localb = lane*4+0; nxt = suf1; }
            unsigned long long ball = __ballot(localb >= 0);
            int hilane = 63 - __clzll(ball);
            if (lane == hilane) {
                prefix_s = prefix | ((unsigned)localb << shift);
                need_s = need - (int)nxt;
            }
        }
        __syncthreads();
    }
    unsigned T = prefix_s;
    int r = need_s;
    __shared__ int cgt, ceq;
    if (tid == 0) { cgt = 0; ceq = 0; }
    __syncthreads();
    int* out = topk + bh * U;
#pragma unroll
    for (int j = 0; j < 8; ++j) {
        if (key[j] > T) { int p = atomicAdd(&cgt, 1); out[p] = tid + 256 * j; }
        else if (key[j] == T) { int e = atomicAdd(&ceq, 1); if (e < r) out[U - r + e] = tid + 256 * j; }
    }
}

// ---------------- Kernel D: split-K partial attention, u-MERGED (R7) ----------------
// Block = (bh, kc of 256 keys); 256 blocks (1/CU, XCD-swizzled), 512 threads.
// ALL 40 queries per block -> K/V chunk staged/read ONCE instead of 5x (the
// old (bh,uc,kc) grid re-staged each chunk per uc: 164MB L2 reads for 64MB of
// unique K/V). No-max softmax kept (scores bounded, R4-verified).
// Score: wave w -> queries 5w..5w+4, lane = key (proven conflict-free layout).
// PV: wave = (u-half, key-quarter); accv[20] per lane (static indexing);
// quarter partials reduced via 20KB LDS buffer per half. pacc/pl layout
// unchanged -> kF identical. No device-scope fences (R5 lesson: ~110us cost).
#define TK 64
__global__ __launch_bounds__(512) void kD_part(const float* __restrict__ Q,
                                               const float* __restrict__ K,
                                               const float* __restrict__ V,
                                               const int* __restrict__ topk,
                                               float* __restrict__ pl,
                                               float* __restrict__ pacc,
                                               int U) {
    int bi = blockIdx.x;
    int xcd = bi & 7, slot = bi >> 3;          // 256 blocks
    int bh = xcd * 4 + (slot >> 3);            // 0..31
    int kc = slot & 7;

    int tid = threadIdx.x;
    int wv = tid >> 6, lane = tid & 63;

    __shared__ float Qs[40 * 64];              // 10 KB
    __shared__ float Ks[TK * 68];              // 17.4 KB, pad 68 (0-conflict proven)
    __shared__ float Ps[40 * 68];              // 10.9 KB
    __shared__ float accbuf[4 * 20 * 64];      // 20.5 KB quarter partials
    __shared__ float lst[40];
    __shared__ int   qidxs[40];

    if (tid < 40) qidxs[tid] = (tid < U) ? topk[bh * U + tid] : 0;
    __syncthreads();
    // stage Q: 40 rows x 64 (reads qidxs; visibility via first post-K barrier)
    for (int i = tid; i < 40 * 64; i += 512) {
        int r = i >> 6, d = i & 63;
        Qs[i] = Q[((long)bh * Lh + qidxs[r]) * Dh + d] * 0.125f;
    }

    int q0 = wv * 5;                           // score-phase queries
    int qtr = wv & 3, uoff = (wv >> 2) * 20;   // PV-phase role
    float plsum[5] = {0.f, 0.f, 0.f, 0.f, 0.f};
    float accv[20];
#pragma unroll
    for (int i = 0; i < 20; ++i) accv[i] = 0.f;

    const long kvbase = (long)bh * Lh * Dh;
    const float4* Kg4 = (const float4*)(K + kvbase);
    const float*  Vg  = V + kvbase;
    int kbase0 = kc * 256;

    for (int t = 0; t < 4; ++t) {
        int t0 = kbase0 + t * TK;
        // ---- stage K tile: 1024 float4s, 2 per thread, coalesced->immediate ----
        int f40 = t0 * (Dh / 4);
#pragma unroll
        for (int j = 0; j < 2; ++j) {
            int i = tid + 512 * j;
            float4 kv = Kg4[f40 + i];
            int row = i >> 4, col = i & 15;
            *(float4*)(&Ks[row * 68 + col * 4]) = kv;
        }
        __syncthreads();                       // Ks+Qs visible; prev Ps reads done

        // ---- scores: this wave's 5 queries at key=lane; p = exp(s) direct ----
        float s[5] = {0.f, 0.f, 0.f, 0.f, 0.f};
#pragma unroll
        for (int j16 = 0; j16 < 16; ++j16) {
            float4 kf = *(const float4*)(&Ks[lane * 68 + j16 * 4]);
#pragma unroll
            for (int qq = 0; qq < 5; ++qq) {
                float4 qv = *(const float4*)(&Qs[(q0 + qq) * 64 + j16 * 4]);
                s[qq] += kf.x*qv.x + kf.y*qv.y + kf.z*qv.z + kf.w*qv.w;
            }
        }
#pragma unroll
        for (int qq = 0; qq < 5; ++qq) {
            float p = __expf(s[qq]);
            plsum[qq] += p;
            Ps[(q0 + qq) * 68 + lane] = p;
        }
        __syncthreads();                       // Ps visible; Ks reads done

        // ---- PV: lane=d; wave=(half,quarter); V direct global (coalesced) ----
        float vk[16];
        int vrow0 = t0 + qtr * 16;
#pragma unroll
        for (int k = 0; k < 16; ++k)
            vk[k] = Vg[(long)(vrow0 + k) * Dh + lane];
#pragma unroll
        for (int u2 = 0; u2 < 20; ++u2) {
            const float* pb = &Ps[(uoff + u2) * 68 + qtr * 16];
            float4 pA = *(const float4*)(pb + 0);
            float4 pB = *(const float4*)(pb + 4);
            float4 pC = *(const float4*)(pb + 8);
            float4 pD = *(const float4*)(pb + 12);
            float ac = accv[u2];
            ac += pA.x*vk[0]  + pA.y*vk[1]  + pA.z*vk[2]  + pA.w*vk[3];
            ac += pB.x*vk[4]  + pB.y*vk[5]  + pB.z*vk[6]  + pB.w*vk[7];
            ac += pC.x*vk[8]  + pC.y*vk[9]  + pC.z*vk[10] + pC.w*vk[11];
            ac += pD.x*vk[12] + pD.y*vk[13] + pD.z*vk[14] + pD.w*vk[15];
            accv[u2] = ac;
        }
        // no barrier: next tile's post-stage barrier orders Ps(t) vs Ps(t+1)
    }

    // l-reduce across the 64 key-lanes for this wave's 5 queries
#pragma unroll
    for (int qq = 0; qq < 5; ++qq) {
        float v = plsum[qq];
#pragma unroll
        for (int off = 1; off < 64; off <<= 1) v += __shfl_xor(v, off);
        if (lane == 0) lst[q0 + qq] = v;
    }

    // quarter-reduce per u-half via accbuf, store pacc (layout = old kF's)
#pragma unroll
    for (int h = 0; h < 2; ++h) {
        if ((wv >> 2) == h) {
#pragma unroll
            for (int u2 = 0; u2 < 20; ++u2)
                accbuf[qtr * 1280 + u2 * 64 + lane] = accv[u2];
        }
        __syncthreads();                       // partials (+lst on h=0) visible
        for (int i = tid; i < 1280; i += 512) {
            float o = accbuf[i] + accbuf[1280 + i] + accbuf[2560 + i] + accbuf[3840 + i];
            int gu = h * 20 + (i >> 6), d = i & 63;
            pacc[((long)(bh * 40 + gu) * 8 + kc) * 64 + d] = o;
        }
        __syncthreads();                       // reads done before h=1 overwrite
    }
    if (tid < 40) pl[(bh * 40 + tid) * 8 + kc] = lst[tid];
}

// ---------------- Kernel F: combine split-K partials (plain sums), scatter ----------
__global__ __launch_bounds__(256) void kF_comb(const float* __restrict__ pl,
                                               const float* __restrict__ pacc,
                                               const int* __restrict__ topk,
                                               float* __restrict__ ctx,
                                               int U, int nch) {
    int bi = blockIdx.x;
    int bh = bi / nch, uc = bi % nch;
    int tid = threadIdx.x;
    int u = tid >> 5, t = tid & 31;
    int gu = uc * 8 + u;
    if (gu >= U) return;
    int qbase = (bh * nch + uc) * 8 + u;
    float gl = 0.f;
#pragma unroll
    for (int kc = 0; kc < 8; ++kc) gl += pl[qbase * 8 + kc];
    float inv = 1.0f / gl;
    float o0 = 0.f, o1 = 0.f;
#pragma unroll
    for (int kc = 0; kc < 8; ++kc) {
        const float* a = pacc + ((long)qbase * 8 + kc) * 64;
        o0 += a[t];
        o1 += a[t + 32];
    }
    int row = topk[bh * U + gu];
    float* crow = ctx + ((long)bh * Lh + row) * Dh;
    crow[t]      = o0 * inv;
    crow[t + 32] = o1 * inv;
}

extern "C" void kernel_launch(void* const* d_in, const int* in_sizes, int n_in,
                              void* d_out, int out_size, void* d_ws, size_t ws_size,
                              hipStream_t stream) {
    const float* Q    = (const float*)d_in[0];
    const float* K    = (const float*)d_in[1];
    const float* V    = (const float*)d_in[2];
    const int*   idxs = (const int*)d_in[3];
    float* ctx = (float*)d_out;

    int u = in_sizes[3] / Lh;    // 40
    int U = u;
    int nch = (U + 7) / 8;       // 5

    // workspace layout (floats)
    float*  wsf   = (float*)d_ws;
    float2* M2    = (float2*)wsf;                    // 131072 float2 = 262144 f
    int*    topk  = (int*)(wsf + 262144);            // 2048 ints
    float*  vpart = wsf + 262144 + 2048;             // 16384 f
    float*  pl    = wsf + 280576;                    // 32*40*8
    float*  pacc  = pl + 32 * 40 * 8;                // 32*40*8*64

    kAC    <<<2304,     256, 0, stream>>>(Q, K, V, idxs, M2, vpart, u);
    kBE    <<<4128,     256, 0, stream>>>(M2, vpart, topk, ctx, U);
    kD_part<<<256,      512, 0, stream>>>(Q, K, V, topk, pl, pacc, U);
    kF_comb<<<BH * nch, 256, 0, stream>>>(pl, pacc, topk, ctx, U, nch);
}